// Round 8
// baseline (135.810 us; speedup 1.0000x reference)
//
#include <hip/hip_runtime.h>

#define NQ 6
#define HID 32
#define SNAPS 16
#define BATCH 1024
#define FSTRIDE 24       // floats per feature vector
#define FTOT 384         // 16 * 24
#define KSTR 24          // K-matrix LDS stride (16B-aligned, <=2-way conflicts = free)
#define KF   192         // per-f block: 8 cols/rows x 24

typedef float v2f __attribute__((ext_vector_type(2)));     // -> v_pk_fma_f32
typedef float vfloat4 __attribute__((ext_vector_type(4))); // nontemporal stores

__device__ __forceinline__ float sigm_f(float x) { return 1.0f / (1.0f + __expf(-x)); }
__device__ __forceinline__ float tanh_f(float x) { return 1.0f - 2.0f / (__expf(2.0f * x) + 1.0f); }

__device__ __forceinline__ void rc_entry(float g, float b0, float b1, float b2,
                                         int i, int j, float& re, float& im) {
    // rc = (I + 3*shadow*B)/2, B = b0*sx + b1*sy + b2*sz ; g = 1.5*shadow
    if (i == j) { re = 0.5f + (i ? -g * b2 : g * b2); im = 0.0f; }
    else        { re = g * b0;  im = (i ? g * b1 : -g * b1); }
}

// Two batch elements per block. Phase 1: waves 0-1 run elem A's LSTM, waves
// 2-3 elem B's (full wave utilization; the two serial wave0-sections run
// concurrently on waves 0 and 2). Phase 2: one sKA/sKB pair reused
// sequentially for the two elements' reconstructions.
__global__ __launch_bounds__(256, 2)
void fused_kernel(const float* __restrict__ snapshot,   // (B,6)
                  const float* __restrict__ bcv,        // (B,6,3)
                  const float* __restrict__ h0,         // (B,32)
                  const float* __restrict__ c0,         // (B,32)
                  const float* __restrict__ W_ih,       // (128,24)
                  const float* __restrict__ W_hh,       // (128,32)
                  const float* __restrict__ b_ih,       // (128)
                  const float* __restrict__ b_hh,       // (128)
                  const float* __restrict__ Wp,         // (6,32,3)
                  const float* __restrict__ bp,         // (6,3)
                  float* __restrict__ out,              // (B,2,64,64)
                  float* __restrict__ out_tail)         // (B,6,3)
{
    __shared__ __align__(16) float sKA[16 * KF];     // 3072 (shared by both elems, sequential)
    __shared__ __align__(16) float sKB[16 * KF];     // 3072
    __shared__ __align__(16) float feat[2][FTOT];    // 768
    __shared__ __align__(16) float sh[2][HID];       // 64
    __shared__ __align__(16) float sg[2][128];       // 256
    __shared__ __align__(16) float sWpT[18 * 36];    // 648
    __shared__ float sbp[18];

    const int t    = threadIdx.x;
    const int w    = t >> 6;
    const int lane = t & 63;
    const int e1   = w >> 1;          // phase-1 element (0 or 1)
    const int wl   = w & 1;           // half of gate rows
    const int b0   = blockIdx.x * 2;
    const int row  = wl * 64 + lane;  // gate row 0..127

    // ---- gate-row weights in VGPRs (v2f -> packed fma) ----
    v2f wih[12], whh[16];
    {
        const v2f* p = (const v2f*)(W_ih + row * 24);
        #pragma unroll
        for (int k = 0; k < 12; ++k) wih[k] = p[k];
        const v2f* q = (const v2f*)(W_hh + row * 32);
        #pragma unroll
        for (int k = 0; k < 16; ++k) whh[k] = q[k];
    }
    const float bias = b_ih[row] + b_hh[row];

    // projection weights -> LDS (transposed, padded stride 36)
    for (int idx = t; idx < NQ * HID * 3; idx += 256) {
        int q = idx / 96, r = idx - q * 96;
        int h = r / 3, s = r - h * 3;
        sWpT[(q * 3 + s) * 36 + h] = Wp[idx];
    }
    if (t < 18) sbp[t] = bp[t];

    float c = 0.0f;
    if (wl == 0) {
        if (lane < 32) { c = c0[(b0 + e1) * 32 + lane]; sh[e1][lane] = h0[(b0 + e1) * 32 + lane]; }
        if (lane < 24)
            feat[e1][lane] = (lane < 6) ? snapshot[(b0 + e1) * 6 + lane]
                                        : bcv[(b0 + e1) * 18 + (lane - 6)];
    }
    __syncthreads();

    // ---- LSTM chains: 15 steps, both elements in lockstep ----
    for (int step = 0; step < SNAPS - 1; ++step) {
        {
            const v2f* x2 = (const v2f*)(feat[e1] + step * FSTRIDE);  // broadcast reads
            const v2f* h2 = (const v2f*)sh[e1];
            v2f g2 = {0.0f, 0.0f};
            #pragma unroll
            for (int k = 0; k < 12; ++k) g2 += x2[k] * wih[k];
            #pragma unroll
            for (int k = 0; k < 16; ++k) g2 += h2[k] * whh[k];
            sg[e1][row] = bias + g2.x + g2.y;
        }
        __syncthreads();

        if (wl == 0) {   // waves 0 and 2: activation + projection + softmax (concurrent)
            if (lane < 32) {
                float gi = sg[e1][lane],      gf = sg[e1][32 + lane];
                float gg = sg[e1][64 + lane], go = sg[e1][96 + lane];
                c = sigm_f(gf) * c + sigm_f(gi) * tanh_f(gg);
                sh[e1][lane] = sigm_f(go) * tanh_f(c);
            }
            __builtin_amdgcn_wave_barrier();   // order in-wave DS: sh write -> reads below
            int rr = (lane < 18) ? lane : 17;
            const v2f* wr = (const v2f*)&sWpT[rr * 36];
            const v2f* h2 = (const v2f*)sh[e1];
            v2f l2 = {0.0f, 0.0f};
            #pragma unroll
            for (int k = 0; k < 16; ++k) l2 += h2[k] * wr[k];
            float logit = ((lane < 18) ? sbp[rr] : 0.0f) + l2.x + l2.y;
            int q3 = 3 * (lane < 6 ? lane : 0);
            float l0 = __shfl(logit, q3), l1 = __shfl(logit, q3 + 1), l2s = __shfl(logit, q3 + 2);
            if (lane < 6) {
                float m = fmaxf(l0, fmaxf(l1, l2s));
                float e0 = __expf(l0 - m), e1x = __expf(l1 - m), e2 = __expf(l2s - m);
                float inv = 1.0f / (e0 + e1x + e2);
                float p0 = e0 * inv, p1 = e1x * inv, p2 = e2 * inv;
                float snap = p0 * p0 + p1 * p1 + p2 * p2;  // tr(M rho Mdag)=sum p^2 (rho unused)
                float* fd = feat[e1] + (step + 1) * FSTRIDE;
                fd[lane] = snap;
                fd[6 + 3 * lane]     = p0;
                fd[6 + 3 * lane + 1] = p1;
                fd[6 + 3 * lane + 2] = p2;
            }
        }
        __syncthreads();
    }

    // ---- tail output: bv of last feature = final probs ----
    if (wl == 0 && lane < 18)
        out_tail[(b0 + e1) * 18 + lane] = feat[e1][15 * FSTRIDE + 6 + lane];

    // ---- phase 2: reconstruct each element sequentially ----
    const int u = t & 15, v = t >> 4;
    const float* baseA = sKA + (u >> 1) * KSTR + 8 * (v >> 3);   // col jA, parity group
    const float* baseB = sKB + (v & 7) * KSTR + 8 * (u & 1);     // row iB, col group

    for (int e = 0; e < 2; ++e) {
        __syncthreads();   // e=0: after phase 1; e=1: protect sKA/sKB from prior reads

        // build KA/KB: 2048 entries, 8 per thread (each wave-iteration = one f)
        for (int n = t; n < 2048; n += 256) {
            int f = n >> 7, r = n & 127;
            int half = r >> 6, a = r & 63;
            const float* fx = &feat[e][f * FSTRIDE];
            int i0 = (a >> 5) & 1, i1 = (a >> 4) & 1, i2 = (a >> 3) & 1;
            int j0 = (a >> 2) & 1, j1 = (a >> 1) & 1, j2 = a & 1;
            int q = 3 * half;
            float g0 = 1.5f * fx[q], g1 = 1.5f * fx[q + 1], g2 = 1.5f * fx[q + 2];
            const float* bb = fx + 6 + 3 * q;
            float r0, m0, r1, m1, r2, m2;
            rc_entry(g0, bb[0], bb[1], bb[2], i0, j0, r0, m0);
            rc_entry(g1, bb[3], bb[4], bb[5], i1, j1, r1, m1);
            rc_entry(g2, bb[6], bb[7], bb[8], i2, j2, r2, m2);
            float pr = r0 * r1 - m0 * m1, pi = r0 * m1 + m0 * r1;
            float qr = pr * r2 - pi * m2, qi = pr * m2 + pi * r2;
            int rw = a >> 3, col = a & 7;
            if (half == 0) {
                // KA: col-major, rows parity-grouped (even at [0..7], odd at [8..15])
                int off = f * KF + col * KSTR + ((rw & 1) ? (7 + rw) : rw);
                sKA[off] = qr; sKA[off + 1] = qi;
            } else {
                int off = f * KF + rw * KSTR + 2 * col;
                sKB[off] = qr; sKB[off + 1] = qi;
            }
        }
        __syncthreads();

        // accumulate: out[i][j] = (1/16) sum_f KA[i>>3][j>>3]*KB[i&7][j&7]
        // i = v + 16k (k<4), j = 4u + d (d<4); packed complex MACs (v_pk_fma_f32)
        v2f acc[4][4];
        #pragma unroll
        for (int k = 0; k < 4; ++k)
            #pragma unroll
            for (int d = 0; d < 4; ++d) acc[k][d] = (v2f){0.0f, 0.0f};

        #pragma unroll 2
        for (int f = 0; f < SNAPS; ++f) {
            const v2f* A = (const v2f*)(baseA + f * KF);
            const v2f* B = (const v2f*)(baseB + f * KF);
            v2f a0 = A[0], a1 = A[1], a2 = A[2], a3 = A[3];
            v2f bq0 = B[0], bq1 = B[1], bq2 = B[2], bq3 = B[3];
            #define CMAC(k, a, d, b)                                   \
                acc[k][d] += (a).x * (b) + ((v2f){-(a).y, (a).y}) * (b).yx;
            #define CROW(k, a)  CMAC(k,a,0,bq0) CMAC(k,a,1,bq1) CMAC(k,a,2,bq2) CMAC(k,a,3,bq3)
            CROW(0, a0) CROW(1, a1) CROW(2, a2) CROW(3, a3)
            #undef CROW
            #undef CMAC
        }

        const float s = 1.0f / 16.0f;
        float* outb = out + (size_t)(b0 + e) * 8192;
        #pragma unroll
        for (int k = 0; k < 4; ++k) {
            int i = v + 16 * k;
            vfloat4 r4 = { acc[k][0].x * s, acc[k][1].x * s, acc[k][2].x * s, acc[k][3].x * s };
            vfloat4 i4 = { acc[k][0].y * s, acc[k][1].y * s, acc[k][2].y * s, acc[k][3].y * s };
            __builtin_nontemporal_store(r4, (vfloat4*)(outb + i * 64 + 4 * u));
            __builtin_nontemporal_store(i4, (vfloat4*)(outb + 4096 + i * 64 + 4 * u));
        }
    }
}

extern "C" void kernel_launch(void* const* d_in, const int* in_sizes, int n_in,
                              void* d_out, int out_size, void* d_ws, size_t ws_size,
                              hipStream_t stream) {
    const float* snapshot = (const float*)d_in[0];
    const float* bcv      = (const float*)d_in[1];
    // d_in[2] = rho — unused: tr(M rho M^dag) = (sum_s p_s^2) tr(rho), tr(rho)=1
    const float* h0       = (const float*)d_in[3];
    const float* c0       = (const float*)d_in[4];
    const float* W_ih     = (const float*)d_in[5];
    const float* W_hh     = (const float*)d_in[6];
    const float* b_ih     = (const float*)d_in[7];
    const float* b_hh     = (const float*)d_in[8];
    const float* Wp       = (const float*)d_in[9];
    const float* bp       = (const float*)d_in[10];
    // d_in[11], d_in[12] = basis_r, basis_i — folded into rc_entry
    float* out = (float*)d_out;

    fused_kernel<<<BATCH / 2, 256, 0, stream>>>(
        snapshot, bcv, h0, c0, W_ih, W_hh, b_ih, b_hh, Wp, bp,
        out, out + (size_t)BATCH * 8192);
}